// Round 14
// baseline (194.628 us; speedup 1.0000x reference)
//
#include <hip/hip_runtime.h>
#include <hip/hip_bf16.h>

#define NTOK 16384
#define NB 16
#define NC 256
#define NK 64
#define EPSF 1e-9f

typedef __attribute__((ext_vector_type(8))) short bf16x8;   // 8 bf16 (4 VGPRs)
typedef __attribute__((ext_vector_type(4))) float f32x4;    // MFMA C/D

__device__ inline unsigned short f2b(float f) {  // RNE f32 -> bf16 bits via HW cvt
  __hip_bfloat16 h = __float2bfloat16(f);
  return *(unsigned short*)&h;
}
__device__ inline float b2f(unsigned short u) {
  union { unsigned u; float f; } v; v.u = ((unsigned)u) << 16; return v.f;
}

// ---------------- Kernel A: weight fusion + Srow zero (unchanged) ----------------
__global__ __launch_bounds__(256) void kA(const float* __restrict__ conv1_w,
                                          const float* __restrict__ conv1_b,
                                          const float* __restrict__ w0,
                                          const float* __restrict__ w1,
                                          const float* __restrict__ b2,
                                          unsigned short* __restrict__ WeffB,
                                          unsigned short* __restrict__ w1Bb,
                                          float* __restrict__ beff,
                                          float* __restrict__ cb,
                                          float* __restrict__ Srow) {
  int blk = blockIdx.x;
  int tid = threadIdx.x;
  if (blk < NK) {
    int k = blk;
    float acc = 0.f;
#pragma unroll 8
    for (int d = 0; d < NC; ++d)
      acc = fmaf(w0[k * NC + d], conv1_w[d * NC + tid], acc);
    WeffB[k * NC + tid] = f2b(acc);
    if (tid == 0) {
      float s = 0.f;
#pragma unroll 8
      for (int d = 0; d < NC; ++d) s = fmaf(w0[k * NC + d], conv1_b[d], s);
      beff[k] = s;
    }
  } else {
    int c = tid;
    float s = 0.f;
#pragma unroll 8
    for (int k = 0; k < NK; ++k) {
      float v = w1[c * NK + k];
      s += v;
      w1Bb[c * NK + k] = f2b(v);
    }
    cb[c] = b2[0] * s;
    for (int i = tid; i < NB * NK; i += 256) Srow[i] = 0.f;
  }
}

// ---------------- Kernel B: 256 tokens/block via np-loop (x page locality) ----------------
// Block owns tokens blockIdx.x*256..+255 (two 128-token tiles; acc/regs reused
// per tile — R5 kF phase-B shape, harness-verified). Per-row x read doubles to
// 1KB contiguous; concurrent readers per DRAM row halve. Grid 64x16 = exactly
// one resident generation at 4 blocks/CU. Epilogue = proven R6 direct stores;
// rowsum accumulated across tiles (reassociation only).
__global__ __launch_bounds__(256) void kB(const float* __restrict__ x,
                                          const unsigned short* __restrict__ WeffB,
                                          const float* __restrict__ beff,
                                          unsigned short* __restrict__ ezg,
                                          float* __restrict__ Srow) {
  const int b = blockIdx.y;
  const int tid = threadIdx.x;
  const int lane = tid & 63;
  const int w = tid >> 6;
  const int l15 = lane & 15;
  const int g = lane >> 4;

  float rs[16];
#pragma unroll
  for (int i = 0; i < 16; ++i) rs[i] = 0.f;

#pragma unroll 1
  for (int np = 0; np < 2; ++np) {
    const int n0 = blockIdx.x * 256 + np * 128 + w * 32;
    const float* xb = x + (((size_t)b * NC) << 14) + n0 + 2 * l15;

    f32x4 acc[4][2];
#pragma unroll
    for (int kf = 0; kf < 4; ++kf)
#pragma unroll
      for (int nf = 0; nf < 2; ++nf)
        acc[kf][nf] = (f32x4){0.f, 0.f, 0.f, 0.f};

    float2 xp[8];
#pragma unroll
    for (int e = 0; e < 8; ++e)
      xp[e] = *(const float2*)(xb + (((size_t)(g * 8 + e)) << 14));

#pragma unroll
    for (int s = 0; s < 8; ++s) {
      const int c0 = s * 32;
      bf16x8 a[4];
#pragma unroll
      for (int kf = 0; kf < 4; ++kf)
        a[kf] = *(const bf16x8*)(WeffB + ((kf * 16 + l15) << 8) + c0 + g * 8);

      float2 xn[8];
      if (s < 7) {
#pragma unroll
        for (int e = 0; e < 8; ++e)
          xn[e] = *(const float2*)(xb + (((size_t)(c0 + 32 + g * 8 + e)) << 14));
      }

      bf16x8 b0, b1;
#pragma unroll
      for (int e = 0; e < 8; ++e) {
        b0[e] = (short)f2b(xp[e].x);
        b1[e] = (short)f2b(xp[e].y);
      }

#pragma unroll
      for (int kf = 0; kf < 4; ++kf) {
        acc[kf][0] = __builtin_amdgcn_mfma_f32_16x16x32_bf16(a[kf], b0, acc[kf][0], 0, 0, 0);
        acc[kf][1] = __builtin_amdgcn_mfma_f32_16x16x32_bf16(a[kf], b1, acc[kf][1], 0, 0, 0);
      }

      if (s < 7) {
#pragma unroll
        for (int e = 0; e < 8; ++e) xp[e] = xn[e];
      }
    }

    // per-tile epilogue (R6 form): exp, pack pair, direct u32 store, rowsum +=
#pragma unroll
    for (int kf = 0; kf < 4; ++kf) {
#pragma unroll
      for (int j = 0; j < 4; ++j) {
        const int k = kf * 16 + g * 4 + j;
        const float bv = beff[k];
        float e0 = __expf(acc[kf][0][j] + bv);
        float e1 = __expf(acc[kf][1][j] + bv);
        unsigned pk = (unsigned)f2b(e0) | ((unsigned)f2b(e1) << 16);
        *(unsigned*)(ezg + (((size_t)(b * NK + k)) << 14) + n0 + 2 * l15) = pk;
        rs[kf * 4 + j] += e0 + e1;
      }
    }
  }

  __shared__ float sred[4][NK];
#pragma unroll
  for (int m = 1; m < 16; m <<= 1) {
#pragma unroll
    for (int i = 0; i < 16; ++i)
      rs[i] += __shfl_xor(rs[i], m, 64);
  }
  if (l15 == 0) {
#pragma unroll
    for (int i = 0; i < 16; ++i)
      sred[w][(i >> 2) * 16 + g * 4 + (i & 3)] = rs[i];
  }
  __syncthreads();
  if (tid < NK)
    atomicAdd(&Srow[b * NK + tid],
              sred[0][tid] + sred[1][tid] + sred[2][tid] + sred[3][tid]);
}

// ---------------- Kernel CD: round-9 proven version (byte-identical) ----------------
__global__ __launch_bounds__(256) void kCD(const unsigned short* __restrict__ ezg,
                                           const float* __restrict__ Srow,
                                           const unsigned short* __restrict__ w1Bb,
                                           const float* __restrict__ cb,
                                           const float* __restrict__ w2,
                                           float* __restrict__ out) {
  const int sl = blockIdx.x;
  const int b  = blockIdx.y;
  const int tid = threadIdx.x;
  const int lane = tid & 63, wv = tid >> 6, l15 = lane & 15, g = lane >> 4;

  __shared__ unsigned short slab[NK * 256];
  __shared__ float invS[NK];

  if (tid < NK) invS[tid] = 1.f / Srow[b * NK + tid];

  const size_t ebase = ((size_t)b * NK) << 14;
#pragma unroll
  for (int p = 0; p < 8; ++p) {
    int idx = p * 256 + tid;
    int k = idx >> 5, ch = idx & 31;
    float4 v = *(const float4*)(ezg + ebase + (((size_t)k) << 14) + sl * 256 + ch * 8);
    int off = (ch * 16) ^ ((((k & 1) << 2) | (ch >> 3)) << 4);
    *(float4*)((char*)slab + k * 512 + off) = v;
  }
  __syncthreads();

  {
    const int nu = tid;
    const int xb2 = (nu >> 6) & 3;
    float s = 0.f;
#pragma unroll
    for (int k = 0; k < NK; ++k) {
      int o = (nu * 2) ^ ((((k & 1) << 2) | xb2) << 4);
      s += b2f(*(const unsigned short*)((const char*)slab + k * 512 + o)) * invS[k];
    }
    const float scv = w2[0] / (EPSF + s);
#pragma unroll
    for (int k = 0; k < NK; ++k) {
      int o = (nu * 2) ^ ((((k & 1) << 2) | xb2) << 4);
      unsigned short* p = (unsigned short*)((char*)slab + k * 512 + o);
      *p = f2b(b2f(*p) * invS[k] * scv);
    }
  }
  __syncthreads();

#pragma unroll 1
  for (int ct = 0; ct < 4; ++ct) {
    const int c0 = ct * 64;
    bf16x8 bfr[4][2];
#pragma unroll
    for (int cc = 0; cc < 4; ++cc)
#pragma unroll
      for (int kh = 0; kh < 2; ++kh)
        bfr[cc][kh] = *(const bf16x8*)(w1Bb + (c0 + cc * 16 + l15) * NK + kh * 32 + g * 8);

    f32x4 acc[4][4];
#pragma unroll
    for (int mi = 0; mi < 4; ++mi)
#pragma unroll
      for (int cc = 0; cc < 4; ++cc)
        acc[mi][cc] = (f32x4){0.f, 0.f, 0.f, 0.f};

#pragma unroll
    for (int mi = 0; mi < 4; ++mi) {
      const int row = wv * 64 + mi * 16 + l15;
      const int ko = row >> 2, t = row & 3;
      const int swz = ((ko & 1) << 2) | t;
      const int off0 = (t * 128 + g * 16) ^ (swz << 4);
      const int off1 = (t * 128 + 64 + g * 16) ^ (swz << 4);
      bf16x8 a0 = *(const bf16x8*)((const char*)slab + ko * 512 + off0);
      bf16x8 a1 = *(const bf16x8*)((const char*)slab + ko * 512 + off1);
#pragma unroll
      for (int cc = 0; cc < 4; ++cc) {
        acc[mi][cc] = __builtin_amdgcn_mfma_f32_16x16x32_bf16(a0, bfr[cc][0], acc[mi][cc], 0, 0, 0);
        acc[mi][cc] = __builtin_amdgcn_mfma_f32_16x16x32_bf16(a1, bfr[cc][1], acc[mi][cc], 0, 0, 0);
      }
    }

#pragma unroll
    for (int mi = 0; mi < 4; ++mi) {
#pragma unroll
      for (int j = 0; j < 4; ++j) {
        const int row = wv * 64 + mi * 16 + g * 4 + j;
        const int ko = row >> 2, t = row & 3;
        float* op = out + ((size_t)b * NTOK + (size_t)ko * 256 + sl * 4 + t) * NC;
#pragma unroll
        for (int cc = 0; cc < 4; ++cc) {
          const int c = c0 + cc * 16 + l15;
          op[c] = acc[mi][cc][j] + cb[c];
        }
      }
    }
  }
}

extern "C" void kernel_launch(void* const* d_in, const int* in_sizes, int n_in,
                              void* d_out, int out_size, void* d_ws, size_t ws_size,
                              hipStream_t stream) {
  const float* x       = (const float*)d_in[0];
  const float* conv1_w = (const float*)d_in[1];
  const float* conv1_b = (const float*)d_in[2];
  const float* w0      = (const float*)d_in[3];
  const float* w2      = (const float*)d_in[4];
  const float* b2      = (const float*)d_in[5];
  const float* w1      = (const float*)d_in[6];
  float* out = (float*)d_out;

  unsigned short* ezg = (unsigned short*)d_ws;                 // 16*64*16384 bf16
  float* beff = (float*)(ezg + (size_t)NB * NK * NTOK);        // 64
  float* cb   = beff + NK;                                     // 256
  float* Srow = cb + NC;                                       // 1024
  unsigned short* WeffB = (unsigned short*)(Srow + NB * NK);   // 64*256 bf16
  unsigned short* w1Bb  = WeffB + NK * NC;                     // 256*64 bf16

  hipLaunchKernelGGL(kA, dim3(65), dim3(256), 0, stream,
                     conv1_w, conv1_b, w0, w1, b2, WeffB, w1Bb, beff, cb, Srow);
  hipLaunchKernelGGL(kB, dim3(64, NB), dim3(256), 0, stream, x, WeffB, beff, ezg, Srow);
  hipLaunchKernelGGL(kCD, dim3(64, NB), dim3(256), 0, stream, ezg, Srow, w1Bb, cb, w2, out);
}

// Round 16
// 169.996 us; speedup vs baseline: 1.1449x; 1.1449x over previous
//
#include <hip/hip_runtime.h>
#include <hip/hip_bf16.h>

#define NTOK 16384
#define NB 16
#define NC 256
#define NK 64
#define EPSF 1e-9f

typedef __attribute__((ext_vector_type(8))) short bf16x8;   // 8 bf16 (4 VGPRs)
typedef __attribute__((ext_vector_type(4))) float f32x4;    // MFMA C/D

__device__ inline unsigned short f2b(float f) {  // RNE f32 -> bf16 bits via HW cvt
  __hip_bfloat16 h = __float2bfloat16(f);
  return *(unsigned short*)&h;
}
__device__ inline float b2f(unsigned short u) {
  union { unsigned u; float f; } v; v.u = ((unsigned)u) << 16; return v.f;
}

__device__ inline void gl_lds16(const float* g, float* l) {
  __builtin_amdgcn_global_load_lds((const __attribute__((address_space(1))) void*)g,
                                   (__attribute__((address_space(3))) void*)l, 16, 0, 0);
}

// ---------------- Kernel A: weight fusion + Srow zero (unchanged) ----------------
__global__ __launch_bounds__(256) void kA(const float* __restrict__ conv1_w,
                                          const float* __restrict__ conv1_b,
                                          const float* __restrict__ w0,
                                          const float* __restrict__ w1,
                                          const float* __restrict__ b2,
                                          unsigned short* __restrict__ WeffB,
                                          unsigned short* __restrict__ w1Bb,
                                          float* __restrict__ beff,
                                          float* __restrict__ cb,
                                          float* __restrict__ Srow) {
  int blk = blockIdx.x;
  int tid = threadIdx.x;
  if (blk < NK) {
    int k = blk;
    float acc = 0.f;
#pragma unroll 8
    for (int d = 0; d < NC; ++d)
      acc = fmaf(w0[k * NC + d], conv1_w[d * NC + tid], acc);
    WeffB[k * NC + tid] = f2b(acc);
    if (tid == 0) {
      float s = 0.f;
#pragma unroll 8
      for (int d = 0; d < NC; ++d) s = fmaf(w0[k * NC + d], conv1_b[d], s);
      beff[k] = s;
    }
  } else {
    int c = tid;
    float s = 0.f;
#pragma unroll 8
    for (int k = 0; k < NK; ++k) {
      float v = w1[c * NK + k];
      s += v;
      w1Bb[c * NK + k] = f2b(v);
    }
    cb[c] = b2[0] * s;
    for (int i = tid; i < NB * NK; i += 256) Srow[i] = 0.f;
  }
}

// ---------------- Kernel B: global_load_lds-staged x (MLP fix, dest-stride FIXED) ----------------
// Bug in R15: LDS dest strided by thread-index (i*256+wv*64 floats) instead of
// byte coverage. Correct: each wave writes 64 lanes x 16B = 256 floats, so the
// wave-uniform dest is xsf + i*1024 + wv*256 (HW adds lane*16B). Flat layout:
// lds_off = idx*16B since row = 128 floats = 512B exactly.
// Everything else identical to R15's design: 16KB in flight per block with no
// VGPR destinations; B-fragments as float2 LDS reads; epilogue = R9 form.
__global__ __launch_bounds__(256) void kB(const float* __restrict__ x,
                                          const unsigned short* __restrict__ WeffB,
                                          const float* __restrict__ beff,
                                          unsigned short* __restrict__ ezg,
                                          float* __restrict__ Srow) {
  const int b = blockIdx.y;
  const int tid = threadIdx.x;
  const int lane = tid & 63;
  const int wv = tid >> 6;
  const int l15 = lane & 15;
  const int g = lane >> 4;

  __shared__ float xs[2][32][128];   // 32 KB staging [buf][ch][tok]
  __shared__ float sred[4][NK];      // 1 KB

  const float* xsrc = x + (((size_t)b * NC) << 14) + blockIdx.x * 128;
  float* xsf = &xs[0][0][0];

  // prologue: stage s=0 into buf 0 (dest: wave-uniform base + lane*16B by HW)
#pragma unroll
  for (int i = 0; i < 4; ++i) {
    const int idx = i * 256 + tid;
    gl_lds16(xsrc + (((size_t)(idx >> 5)) << 14) + (idx & 31) * 4,
             xsf + i * 1024 + wv * 256);
  }
  __syncthreads();

  f32x4 acc[4][2];
#pragma unroll
  for (int kf = 0; kf < 4; ++kf)
#pragma unroll
    for (int nf = 0; nf < 2; ++nf)
      acc[kf][nf] = (f32x4){0.f, 0.f, 0.f, 0.f};

  int buf = 0;
#pragma unroll
  for (int s = 0; s < 8; ++s) {
    // issue next tile's staging loads (fly under compute + barrier wait)
    if (s < 7) {
      const float* base = xsrc + (((size_t)((s + 1) * 32)) << 14);
      float* dstf = &xs[buf ^ 1][0][0];
#pragma unroll
      for (int i = 0; i < 4; ++i) {
        const int idx = i * 256 + tid;
        gl_lds16(base + (((size_t)(idx >> 5)) << 14) + (idx & 31) * 4,
                 dstf + i * 1024 + wv * 256);
      }
    }

    const int c0 = s * 32;
    bf16x8 a[4];
#pragma unroll
    for (int kf = 0; kf < 4; ++kf)
      a[kf] = *(const bf16x8*)(WeffB + ((kf * 16 + l15) << 8) + c0 + g * 8);

    bf16x8 b0, b1;
#pragma unroll
    for (int e = 0; e < 8; ++e) {
      float2 xv = *(const float2*)&xs[buf][g * 8 + e][wv * 32 + 2 * l15];
      b0[e] = (short)f2b(xv.x);
      b1[e] = (short)f2b(xv.y);
    }

#pragma unroll
    for (int kf = 0; kf < 4; ++kf) {
      acc[kf][0] = __builtin_amdgcn_mfma_f32_16x16x32_bf16(a[kf], b0, acc[kf][0], 0, 0, 0);
      acc[kf][1] = __builtin_amdgcn_mfma_f32_16x16x32_bf16(a[kf], b1, acc[kf][1], 0, 0, 0);
    }

    __syncthreads();   // stage(s+1) landed; buf readers done -> safe to swap
    buf ^= 1;
  }

  // epilogue (R9 form); staging LDS is dead -> alias ezs onto it
  unsigned* ezs = (unsigned*)xsf;    // NK*65 dwords = 16.25KB < 32KB
  const int n0 = blockIdx.x * 128 + wv * 32;
  (void)n0;
  float rs[16];
#pragma unroll
  for (int kf = 0; kf < 4; ++kf) {
#pragma unroll
    for (int j = 0; j < 4; ++j) {
      const int k = kf * 16 + g * 4 + j;
      const float bv = beff[k];
      float e0 = __expf(acc[kf][0][j] + bv);
      float e1 = __expf(acc[kf][1][j] + bv);
      ezs[k * 65 + wv * 16 + l15] = (unsigned)f2b(e0) | ((unsigned)f2b(e1) << 16);
      rs[kf * 4 + j] = e0 + e1;
    }
  }
#pragma unroll
  for (int m = 1; m < 16; m <<= 1) {
#pragma unroll
    for (int i = 0; i < 16; ++i)
      rs[i] += __shfl_xor(rs[i], m, 64);
  }
  if (l15 == 0) {
#pragma unroll
    for (int i = 0; i < 16; ++i)
      sred[wv][(i >> 2) * 16 + g * 4 + (i & 3)] = rs[i];
  }
  __syncthreads();

  const int blkbase = blockIdx.x * 128;
#pragma unroll
  for (int i = 0; i < 4; ++i) {
    const int idx = i * 256 + tid;
    const int k = idx >> 4, ch = idx & 15;
    uint4 v;
    v.x = ezs[k * 65 + ch * 4 + 0];
    v.y = ezs[k * 65 + ch * 4 + 1];
    v.z = ezs[k * 65 + ch * 4 + 2];
    v.w = ezs[k * 65 + ch * 4 + 3];
    *(uint4*)(ezg + (((size_t)(b * NK + k)) << 14) + blkbase + ch * 8) = v;
  }

  if (tid < NK)
    atomicAdd(&Srow[b * NK + tid],
              sred[0][tid] + sred[1][tid] + sred[2][tid] + sred[3][tid]);
}

// ---------------- Kernel CD: round-9 proven version (byte-identical) ----------------
__global__ __launch_bounds__(256) void kCD(const unsigned short* __restrict__ ezg,
                                           const float* __restrict__ Srow,
                                           const unsigned short* __restrict__ w1Bb,
                                           const float* __restrict__ cb,
                                           const float* __restrict__ w2,
                                           float* __restrict__ out) {
  const int sl = blockIdx.x;
  const int b  = blockIdx.y;
  const int tid = threadIdx.x;
  const int lane = tid & 63, wv = tid >> 6, l15 = lane & 15, g = lane >> 4;

  __shared__ unsigned short slab[NK * 256];
  __shared__ float invS[NK];

  if (tid < NK) invS[tid] = 1.f / Srow[b * NK + tid];

  const size_t ebase = ((size_t)b * NK) << 14;
#pragma unroll
  for (int p = 0; p < 8; ++p) {
    int idx = p * 256 + tid;
    int k = idx >> 5, ch = idx & 31;
    float4 v = *(const float4*)(ezg + ebase + (((size_t)k) << 14) + sl * 256 + ch * 8);
    int off = (ch * 16) ^ ((((k & 1) << 2) | (ch >> 3)) << 4);
    *(float4*)((char*)slab + k * 512 + off) = v;
  }
  __syncthreads();

  {
    const int nu = tid;
    const int xb2 = (nu >> 6) & 3;
    float s = 0.f;
#pragma unroll
    for (int k = 0; k < NK; ++k) {
      int o = (nu * 2) ^ ((((k & 1) << 2) | xb2) << 4);
      s += b2f(*(const unsigned short*)((const char*)slab + k * 512 + o)) * invS[k];
    }
    const float scv = w2[0] / (EPSF + s);
#pragma unroll
    for (int k = 0; k < NK; ++k) {
      int o = (nu * 2) ^ ((((k & 1) << 2) | xb2) << 4);
      unsigned short* p = (unsigned short*)((char*)slab + k * 512 + o);
      *p = f2b(b2f(*p) * invS[k] * scv);
    }
  }
  __syncthreads();

#pragma unroll 1
  for (int ct = 0; ct < 4; ++ct) {
    const int c0 = ct * 64;
    bf16x8 bfr[4][2];
#pragma unroll
    for (int cc = 0; cc < 4; ++cc)
#pragma unroll
      for (int kh = 0; kh < 2; ++kh)
        bfr[cc][kh] = *(const bf16x8*)(w1Bb + (c0 + cc * 16 + l15) * NK + kh * 32 + g * 8);

    f32x4 acc[4][4];
#pragma unroll
    for (int mi = 0; mi < 4; ++mi)
#pragma unroll
      for (int cc = 0; cc < 4; ++cc)
        acc[mi][cc] = (f32x4){0.f, 0.f, 0.f, 0.f};

#pragma unroll
    for (int mi = 0; mi < 4; ++mi) {
      const int row = wv * 64 + mi * 16 + l15;
      const int ko = row >> 2, t = row & 3;
      const int swz = ((ko & 1) << 2) | t;
      const int off0 = (t * 128 + g * 16) ^ (swz << 4);
      const int off1 = (t * 128 + 64 + g * 16) ^ (swz << 4);
      bf16x8 a0 = *(const bf16x8*)((const char*)slab + ko * 512 + off0);
      bf16x8 a1 = *(const bf16x8*)((const char*)slab + ko * 512 + off1);
#pragma unroll
      for (int cc = 0; cc < 4; ++cc) {
        acc[mi][cc] = __builtin_amdgcn_mfma_f32_16x16x32_bf16(a0, bfr[cc][0], acc[mi][cc], 0, 0, 0);
        acc[mi][cc] = __builtin_amdgcn_mfma_f32_16x16x32_bf16(a1, bfr[cc][1], acc[mi][cc], 0, 0, 0);
      }
    }

#pragma unroll
    for (int mi = 0; mi < 4; ++mi) {
#pragma unroll
      for (int j = 0; j < 4; ++j) {
        const int row = wv * 64 + mi * 16 + g * 4 + j;
        const int ko = row >> 2, t = row & 3;
        float* op = out + ((size_t)b * NTOK + (size_t)ko * 256 + sl * 4 + t) * NC;
#pragma unroll
        for (int cc = 0; cc < 4; ++cc) {
          const int c = c0 + cc * 16 + l15;
          op[c] = acc[mi][cc][j] + cb[c];
        }
      }
    }
  }
}

extern "C" void kernel_launch(void* const* d_in, const int* in_sizes, int n_in,
                              void* d_out, int out_size, void* d_ws, size_t ws_size,
                              hipStream_t stream) {
  const float* x       = (const float*)d_in[0];
  const float* conv1_w = (const float*)d_in[1];
  const float* conv1_b = (const float*)d_in[2];
  const float* w0      = (const float*)d_in[3];
  const float* w2      = (const float*)d_in[4];
  const float* b2      = (const float*)d_in[5];
  const float* w1      = (const float*)d_in[6];
  float* out = (float*)d_out;

  unsigned short* ezg = (unsigned short*)d_ws;                 // 16*64*16384 bf16
  float* beff = (float*)(ezg + (size_t)NB * NK * NTOK);        // 64
  float* cb   = beff + NK;                                     // 256
  float* Srow = cb + NC;                                       // 1024
  unsigned short* WeffB = (unsigned short*)(Srow + NB * NK);   // 64*256 bf16
  unsigned short* w1Bb  = WeffB + NK * NC;                     // 256*64 bf16

  hipLaunchKernelGGL(kA, dim3(65), dim3(256), 0, stream,
                     conv1_w, conv1_b, w0, w1, b2, WeffB, w1Bb, beff, cb, Srow);
  hipLaunchKernelGGL(kB, dim3(128, NB), dim3(256), 0, stream, x, WeffB, beff, ezg, Srow);
  hipLaunchKernelGGL(kCD, dim3(64, NB), dim3(256), 0, stream, ezg, Srow, w1Bb, cb, w2, out);
}

// Round 17
// 141.067 us; speedup vs baseline: 1.3797x; 1.2051x over previous
//
#include <hip/hip_runtime.h>
#include <hip/hip_bf16.h>

#define NTOK 16384
#define NB 16
#define NC 256
#define NK 64
#define EPSF 1e-9f

typedef __attribute__((ext_vector_type(8))) short bf16x8;   // 8 bf16 (4 VGPRs)
typedef __attribute__((ext_vector_type(4))) float f32x4;    // MFMA C/D
typedef __attribute__((ext_vector_type(2))) float f32x2;    // nt-loadable float2

__device__ inline unsigned short f2b(float f) {  // RNE f32 -> bf16 bits via HW cvt
  __hip_bfloat16 h = __float2bfloat16(f);
  return *(unsigned short*)&h;
}
__device__ inline float b2f(unsigned short u) {
  union { unsigned u; float f; } v; v.u = ((unsigned)u) << 16; return v.f;
}

// ---------------- Kernel A: weight fusion + Srow zero (unchanged) ----------------
__global__ __launch_bounds__(256) void kA(const float* __restrict__ conv1_w,
                                          const float* __restrict__ conv1_b,
                                          const float* __restrict__ w0,
                                          const float* __restrict__ w1,
                                          const float* __restrict__ b2,
                                          unsigned short* __restrict__ WeffB,
                                          unsigned short* __restrict__ w1Bb,
                                          float* __restrict__ beff,
                                          float* __restrict__ cb,
                                          float* __restrict__ Srow) {
  int blk = blockIdx.x;
  int tid = threadIdx.x;
  if (blk < NK) {
    int k = blk;
    float acc = 0.f;
#pragma unroll 8
    for (int d = 0; d < NC; ++d)
      acc = fmaf(w0[k * NC + d], conv1_w[d * NC + tid], acc);
    WeffB[k * NC + tid] = f2b(acc);
    if (tid == 0) {
      float s = 0.f;
#pragma unroll 8
      for (int d = 0; d < NC; ++d) s = fmaf(w0[k * NC + d], conv1_b[d], s);
      beff[k] = s;
    }
  } else {
    int c = tid;
    float s = 0.f;
#pragma unroll 8
    for (int k = 0; k < NK; ++k) {
      float v = w1[c * NK + k];
      s += v;
      w1Bb[c * NK + k] = f2b(v);
    }
    cb[c] = b2[0] * s;
    for (int i = tid; i < NB * NK; i += 256) Srow[i] = 0.f;
  }
}

// ---------------- Kernel B: R9 proven structure + NON-TEMPORAL x loads ----------------
// ONLY change vs the 167.4us R9 baseline: x float2 loads use
// __builtin_nontemporal_load so the 268MB read-once stream doesn't allocate in
// L2, preserving L2 for the concurrently-written ez stream and WeffB re-reads.
// Same addresses, instruction count, and values.
__global__ __launch_bounds__(256) void kB(const float* __restrict__ x,
                                          const unsigned short* __restrict__ WeffB,
                                          const float* __restrict__ beff,
                                          unsigned short* __restrict__ ezg,
                                          float* __restrict__ Srow) {
  const int b = blockIdx.y;
  const int tid = threadIdx.x;
  const int lane = tid & 63;
  const int w = tid >> 6;
  const int l15 = lane & 15;
  const int g = lane >> 4;
  const int n0 = blockIdx.x * 128 + w * 32;

  const float* xb = x + (((size_t)b * NC) << 14) + n0 + 2 * l15;

  f32x4 acc[4][2];
#pragma unroll
  for (int kf = 0; kf < 4; ++kf)
#pragma unroll
    for (int nf = 0; nf < 2; ++nf)
      acc[kf][nf] = (f32x4){0.f, 0.f, 0.f, 0.f};

  f32x2 xp[8];
#pragma unroll
  for (int e = 0; e < 8; ++e)
    xp[e] = __builtin_nontemporal_load((const f32x2*)(xb + (((size_t)(g * 8 + e)) << 14)));

#pragma unroll
  for (int s = 0; s < 8; ++s) {
    const int c0 = s * 32;
    bf16x8 a[4];
#pragma unroll
    for (int kf = 0; kf < 4; ++kf)
      a[kf] = *(const bf16x8*)(WeffB + ((kf * 16 + l15) << 8) + c0 + g * 8);

    f32x2 xn[8];
    if (s < 7) {
#pragma unroll
      for (int e = 0; e < 8; ++e)
        xn[e] = __builtin_nontemporal_load((const f32x2*)(xb + (((size_t)(c0 + 32 + g * 8 + e)) << 14)));
    }

    bf16x8 b0, b1;
#pragma unroll
    for (int e = 0; e < 8; ++e) {
      b0[e] = (short)f2b(xp[e][0]);
      b1[e] = (short)f2b(xp[e][1]);
    }

#pragma unroll
    for (int kf = 0; kf < 4; ++kf) {
      acc[kf][0] = __builtin_amdgcn_mfma_f32_16x16x32_bf16(a[kf], b0, acc[kf][0], 0, 0, 0);
      acc[kf][1] = __builtin_amdgcn_mfma_f32_16x16x32_bf16(a[kf], b1, acc[kf][1], 0, 0, 0);
    }

    if (s < 7) {
#pragma unroll
      for (int e = 0; e < 8; ++e) xp[e] = xn[e];
    }
  }

  // epilogue: exp + pack into LDS (stride-65 dwords), wide uint4 ez stores (R9)
  __shared__ unsigned ezs[NK * 65];
  __shared__ float sred[4][NK];
  float rs[16];
#pragma unroll
  for (int kf = 0; kf < 4; ++kf) {
#pragma unroll
    for (int j = 0; j < 4; ++j) {
      const int k = kf * 16 + g * 4 + j;
      const float bv = beff[k];
      float e0 = __expf(acc[kf][0][j] + bv);
      float e1 = __expf(acc[kf][1][j] + bv);
      ezs[k * 65 + w * 16 + l15] = (unsigned)f2b(e0) | ((unsigned)f2b(e1) << 16);
      rs[kf * 4 + j] = e0 + e1;
    }
  }
#pragma unroll
  for (int m = 1; m < 16; m <<= 1) {
#pragma unroll
    for (int i = 0; i < 16; ++i)
      rs[i] += __shfl_xor(rs[i], m, 64);
  }
  if (l15 == 0) {
#pragma unroll
    for (int i = 0; i < 16; ++i)
      sred[w][(i >> 2) * 16 + g * 4 + (i & 3)] = rs[i];
  }
  __syncthreads();

  const int blkbase = blockIdx.x * 128;
#pragma unroll
  for (int i = 0; i < 4; ++i) {
    const int idx = i * 256 + tid;
    const int k = idx >> 4, ch = idx & 15;
    uint4 v;
    v.x = ezs[k * 65 + ch * 4 + 0];
    v.y = ezs[k * 65 + ch * 4 + 1];
    v.z = ezs[k * 65 + ch * 4 + 2];
    v.w = ezs[k * 65 + ch * 4 + 3];
    *(uint4*)(ezg + (((size_t)(b * NK + k)) << 14) + blkbase + ch * 8) = v;
  }

  if (tid < NK)
    atomicAdd(&Srow[b * NK + tid],
              sred[0][tid] + sred[1][tid] + sred[2][tid] + sred[3][tid]);
}

// ---------------- Kernel CD: round-9 proven version (byte-identical) ----------------
__global__ __launch_bounds__(256) void kCD(const unsigned short* __restrict__ ezg,
                                           const float* __restrict__ Srow,
                                           const unsigned short* __restrict__ w1Bb,
                                           const float* __restrict__ cb,
                                           const float* __restrict__ w2,
                                           float* __restrict__ out) {
  const int sl = blockIdx.x;
  const int b  = blockIdx.y;
  const int tid = threadIdx.x;
  const int lane = tid & 63, wv = tid >> 6, l15 = lane & 15, g = lane >> 4;

  __shared__ unsigned short slab[NK * 256];
  __shared__ float invS[NK];

  if (tid < NK) invS[tid] = 1.f / Srow[b * NK + tid];

  const size_t ebase = ((size_t)b * NK) << 14;
#pragma unroll
  for (int p = 0; p < 8; ++p) {
    int idx = p * 256 + tid;
    int k = idx >> 5, ch = idx & 31;
    float4 v = *(const float4*)(ezg + ebase + (((size_t)k) << 14) + sl * 256 + ch * 8);
    int off = (ch * 16) ^ ((((k & 1) << 2) | (ch >> 3)) << 4);
    *(float4*)((char*)slab + k * 512 + off) = v;
  }
  __syncthreads();

  {
    const int nu = tid;
    const int xb2 = (nu >> 6) & 3;
    float s = 0.f;
#pragma unroll
    for (int k = 0; k < NK; ++k) {
      int o = (nu * 2) ^ ((((k & 1) << 2) | xb2) << 4);
      s += b2f(*(const unsigned short*)((const char*)slab + k * 512 + o)) * invS[k];
    }
    const float scv = w2[0] / (EPSF + s);
#pragma unroll
    for (int k = 0; k < NK; ++k) {
      int o = (nu * 2) ^ ((((k & 1) << 2) | xb2) << 4);
      unsigned short* p = (unsigned short*)((char*)slab + k * 512 + o);
      *p = f2b(b2f(*p) * invS[k] * scv);
    }
  }
  __syncthreads();

#pragma unroll 1
  for (int ct = 0; ct < 4; ++ct) {
    const int c0 = ct * 64;
    bf16x8 bfr[4][2];
#pragma unroll
    for (int cc = 0; cc < 4; ++cc)
#pragma unroll
      for (int kh = 0; kh < 2; ++kh)
        bfr[cc][kh] = *(const bf16x8*)(w1Bb + (c0 + cc * 16 + l15) * NK + kh * 32 + g * 8);

    f32x4 acc[4][4];
#pragma unroll
    for (int mi = 0; mi < 4; ++mi)
#pragma unroll
      for (int cc = 0; cc < 4; ++cc)
        acc[mi][cc] = (f32x4){0.f, 0.f, 0.f, 0.f};

#pragma unroll
    for (int mi = 0; mi < 4; ++mi) {
      const int row = wv * 64 + mi * 16 + l15;
      const int ko = row >> 2, t = row & 3;
      const int swz = ((ko & 1) << 2) | t;
      const int off0 = (t * 128 + g * 16) ^ (swz << 4);
      const int off1 = (t * 128 + 64 + g * 16) ^ (swz << 4);
      bf16x8 a0 = *(const bf16x8*)((const char*)slab + ko * 512 + off0);
      bf16x8 a1 = *(const bf16x8*)((const char*)slab + ko * 512 + off1);
#pragma unroll
      for (int cc = 0; cc < 4; ++cc) {
        acc[mi][cc] = __builtin_amdgcn_mfma_f32_16x16x32_bf16(a0, bfr[cc][0], acc[mi][cc], 0, 0, 0);
        acc[mi][cc] = __builtin_amdgcn_mfma_f32_16x16x32_bf16(a1, bfr[cc][1], acc[mi][cc], 0, 0, 0);
      }
    }

#pragma unroll
    for (int mi = 0; mi < 4; ++mi) {
#pragma unroll
      for (int j = 0; j < 4; ++j) {
        const int row = wv * 64 + mi * 16 + g * 4 + j;
        const int ko = row >> 2, t = row & 3;
        float* op = out + ((size_t)b * NTOK + (size_t)ko * 256 + sl * 4 + t) * NC;
#pragma unroll
        for (int cc = 0; cc < 4; ++cc) {
          const int c = c0 + cc * 16 + l15;
          op[c] = acc[mi][cc][j] + cb[c];
        }
      }
    }
  }
}

extern "C" void kernel_launch(void* const* d_in, const int* in_sizes, int n_in,
                              void* d_out, int out_size, void* d_ws, size_t ws_size,
                              hipStream_t stream) {
  const float* x       = (const float*)d_in[0];
  const float* conv1_w = (const float*)d_in[1];
  const float* conv1_b = (const float*)d_in[2];
  const float* w0      = (const float*)d_in[3];
  const float* w2      = (const float*)d_in[4];
  const float* b2      = (const float*)d_in[5];
  const float* w1      = (const float*)d_in[6];
  float* out = (float*)d_out;

  unsigned short* ezg = (unsigned short*)d_ws;                 // 16*64*16384 bf16
  float* beff = (float*)(ezg + (size_t)NB * NK * NTOK);        // 64
  float* cb   = beff + NK;                                     // 256
  float* Srow = cb + NC;                                       // 1024
  unsigned short* WeffB = (unsigned short*)(Srow + NB * NK);   // 64*256 bf16
  unsigned short* w1Bb  = WeffB + NK * NC;                     // 256*64 bf16

  hipLaunchKernelGGL(kA, dim3(65), dim3(256), 0, stream,
                     conv1_w, conv1_b, w0, w1, b2, WeffB, w1Bb, beff, cb, Srow);
  hipLaunchKernelGGL(kB, dim3(128, NB), dim3(256), 0, stream, x, WeffB, beff, ezg, Srow);
  hipLaunchKernelGGL(kCD, dim3(64, NB), dim3(256), 0, stream, ezg, Srow, w1Bb, cb, w2, out);
}